// Round 2
// baseline (302.783 us; speedup 1.0000x reference)
//
#include <hip/hip_runtime.h>

// Focal multi-task loss, B=4194304 rows, C=8 classes, two tasks.
// ALPHA=0.25, GAMMA=2.0, boost class-1 by 1.5, task weights {1.0, 0.5}.
// Memory-bound: ~302 MB read -> ~48us floor at 6.3 TB/s achievable.

#define B_ROWS 4194304
#define NB 1024  // blocks per task; 1024*256 threads -> 16 rows/thread

__global__ __launch_bounds__(256) void focal_partial_kernel(
    const float* __restrict__ logits_dir, const int* __restrict__ labels_dir,
    const float* __restrict__ logits_vol, const int* __restrict__ labels_vol,
    float* __restrict__ partials /* [2][NB] */)
{
    const int task = blockIdx.y;
    const float* __restrict__ logits = task ? logits_vol : logits_dir;
    const int*   __restrict__ labels = task ? labels_vol : labels_dir;

    float acc = 0.0f;
    const int stride = NB * 256;
    for (int r = blockIdx.x * 256 + threadIdx.x; r < B_ROWS; r += stride) {
        const float4 a = *reinterpret_cast<const float4*>(logits + (size_t)r * 8);
        const float4 b = *reinterpret_cast<const float4*>(logits + (size_t)r * 8 + 4);
        const int lab = labels[r];

        const float x0 = a.x, x1 = a.y, x2 = a.z, x3 = a.w;
        const float x4 = b.x, x5 = b.y, x6 = b.z, x7 = b.w;

        // numerically-stable softmax denominator (matches jax.nn.softmax)
        const float m = fmaxf(fmaxf(fmaxf(x0, x1), fmaxf(x2, x3)),
                              fmaxf(fmaxf(x4, x5), fmaxf(x6, x7)));
        const float e0 = expf(x0 - m), e1 = expf(x1 - m);
        const float e2 = expf(x2 - m), e3 = expf(x3 - m);
        const float e4 = expf(x4 - m), e5 = expf(x5 - m);
        const float e6 = expf(x6 - m), e7 = expf(x7 - m);
        const float s = ((e0 + e1) + (e2 + e3)) + ((e4 + e5) + (e6 + e7));

        // select x[lab] via cndmask chain (no runtime-indexed array -> no scratch)
        float xl = x0;
        xl = (lab == 1) ? x1 : xl;
        xl = (lab == 2) ? x2 : xl;
        xl = (lab == 3) ? x3 : xl;
        xl = (lab == 4) ? x4 : xl;
        xl = (lab == 5) ? x5 : xl;
        xl = (lab == 6) ? x6 : xl;
        xl = (lab == 7) ? x7 : xl;

        const float pt = expf(xl - m) * (1.0f / s);
        const float alpha_t = (lab == 0) ? 0.75f : 0.25f;
        const float omp = 1.0f - pt;
        const float focal_w = omp * omp;               // (1-pt)^2.0
        float loss = -alpha_t * focal_w * logf(pt + 1e-8f);
        loss = (lab == 1) ? loss * 1.5f : loss;
        acc += loss;
    }

    // wave (64-lane) shuffle reduce
    #pragma unroll
    for (int off = 32; off > 0; off >>= 1)
        acc += __shfl_down(acc, off);

    __shared__ float lds[4];
    const int lane = threadIdx.x & 63;
    const int wid  = threadIdx.x >> 6;
    if (lane == 0) lds[wid] = acc;
    __syncthreads();
    if (threadIdx.x == 0) {
        const float bsum = (lds[0] + lds[1]) + (lds[2] + lds[3]);
        partials[task * NB + blockIdx.x] = bsum;
    }
}

__global__ __launch_bounds__(256) void focal_final_kernel(
    const float* __restrict__ partials, float* __restrict__ out)
{
    // 256 threads: each sums NB/256 = 4 partials per task in double
    double sd = 0.0, sv = 0.0;
    for (int k = threadIdx.x; k < NB; k += 256) {
        sd += (double)partials[k];
        sv += (double)partials[NB + k];
    }
    #pragma unroll
    for (int off = 32; off > 0; off >>= 1) {
        sd += __shfl_down(sd, off);
        sv += __shfl_down(sv, off);
    }
    __shared__ double lds[8];
    const int lane = threadIdx.x & 63;
    const int wid  = threadIdx.x >> 6;
    if (lane == 0) { lds[wid] = sd; lds[4 + wid] = sv; }
    __syncthreads();
    if (threadIdx.x == 0) {
        const double l_dir = ((lds[0] + lds[1]) + (lds[2] + lds[3])) / (double)B_ROWS;
        const double l_vol = ((lds[4] + lds[5]) + (lds[6] + lds[7])) / (double)B_ROWS;
        out[0] = (float)(l_dir + 0.5 * l_vol);  // total = 1.0*dir + 0.5*vol
        out[1] = (float)l_dir;
        out[2] = (float)l_vol;
    }
}

extern "C" void kernel_launch(void* const* d_in, const int* in_sizes, int n_in,
                              void* d_out, int out_size, void* d_ws, size_t ws_size,
                              hipStream_t stream) {
    const float* logits_dir = (const float*)d_in[0];
    const int*   labels_dir = (const int*)d_in[1];
    const float* logits_vol = (const float*)d_in[2];
    const int*   labels_vol = (const int*)d_in[3];
    float* out = (float*)d_out;
    float* partials = (float*)d_ws;  // 2*NB floats = 8 KB, fully overwritten each call

    dim3 grid(NB, 2);
    focal_partial_kernel<<<grid, 256, 0, stream>>>(logits_dir, labels_dir,
                                                   logits_vol, labels_vol, partials);
    focal_final_kernel<<<1, 256, 0, stream>>>(partials, out);
}

// Round 3
// 297.638 us; speedup vs baseline: 1.0173x; 1.0173x over previous
//
#include <hip/hip_runtime.h>

// Focal multi-task loss, B=4194304 rows, C=8 classes, two tasks.
// ALPHA=0.25, GAMMA=2.0, boost class-1 by 1.5, task weights {1.0, 0.5}.
// Memory-bound floor: ~302 MB read -> ~48us at 6.3 TB/s (less with LLC hits).
// R2: 115us, VGPR=24 -> no pipelining, latency-bound. Fix: 4-row batch + fast exp2/log2.

#define B_ROWS 4194304
#define NB 1024           // blocks per task; 1024*256 threads -> 16 rows/thread
#define STRIDE (NB * 256)

#define LOG2E 1.4426950408889634f
#define LN2   0.6931471805599453f

__device__ __forceinline__ float row_loss(const float4 a, const float4 b, const int lab) {
    const float x0 = a.x, x1 = a.y, x2 = a.z, x3 = a.w;
    const float x4 = b.x, x5 = b.y, x6 = b.z, x7 = b.w;

    const float m = fmaxf(fmaxf(fmaxf(x0, x1), fmaxf(x2, x3)),
                          fmaxf(fmaxf(x4, x5), fmaxf(x6, x7)));
    const float mL = m * LOG2E;
    // e_j = 2^(x_j*log2e - m*log2e) == exp(x_j - m)
    const float e0 = __builtin_amdgcn_exp2f(__builtin_fmaf(x0, LOG2E, -mL));
    const float e1 = __builtin_amdgcn_exp2f(__builtin_fmaf(x1, LOG2E, -mL));
    const float e2 = __builtin_amdgcn_exp2f(__builtin_fmaf(x2, LOG2E, -mL));
    const float e3 = __builtin_amdgcn_exp2f(__builtin_fmaf(x3, LOG2E, -mL));
    const float e4 = __builtin_amdgcn_exp2f(__builtin_fmaf(x4, LOG2E, -mL));
    const float e5 = __builtin_amdgcn_exp2f(__builtin_fmaf(x5, LOG2E, -mL));
    const float e6 = __builtin_amdgcn_exp2f(__builtin_fmaf(x6, LOG2E, -mL));
    const float e7 = __builtin_amdgcn_exp2f(__builtin_fmaf(x7, LOG2E, -mL));
    const float s = ((e0 + e1) + (e2 + e3)) + ((e4 + e5) + (e6 + e7));

    // select e[lab] via cndmask chain (no runtime-indexed array -> no scratch)
    float el = e0;
    el = (lab == 1) ? e1 : el;
    el = (lab == 2) ? e2 : el;
    el = (lab == 3) ? e3 : el;
    el = (lab == 4) ? e4 : el;
    el = (lab == 5) ? e5 : el;
    el = (lab == 6) ? e6 : el;
    el = (lab == 7) ? e7 : el;

    const float pt = el * __builtin_amdgcn_rcpf(s);
    // c = alpha_t * (lab==1 ? 1.5 : 1) * ln2   (fold constants into one coeff)
    float c = (lab == 0) ? (0.75f * LN2) : (0.25f * LN2);
    c = (lab == 1) ? (0.375f * LN2) : c;
    const float omp = 1.0f - pt;
    const float w = omp * omp;                       // (1-pt)^2
    const float lg = __builtin_amdgcn_logf(pt + 1e-8f);  // log2(pt+1e-8)
    return -(c * w) * lg;                            // -alpha*boost*w*ln(pt+1e-8)
}

__global__ __launch_bounds__(256, 8) void focal_partial_kernel(
    const float* __restrict__ logits_dir, const int* __restrict__ labels_dir,
    const float* __restrict__ logits_vol, const int* __restrict__ labels_vol,
    float* __restrict__ partials /* [2][NB] */)
{
    const int task = blockIdx.y;
    const float* __restrict__ logits = task ? logits_vol : logits_dir;
    const int*   __restrict__ labels = task ? labels_vol : labels_dir;

    const int idx = blockIdx.x * 256 + threadIdx.x;
    float acc = 0.0f;

    // 16 rows/thread = 4 outer iters x 4-row batch (all loads issued up front
    // -> 9 loads in flight, 4 independent compute chains; VGPR ~60, occupancy 8w/SIMD)
    #pragma unroll 1
    for (int it = 0; it < 4; ++it) {
        const int r0 = idx + (it * 4 + 0) * STRIDE;
        const int r1 = idx + (it * 4 + 1) * STRIDE;
        const int r2 = idx + (it * 4 + 2) * STRIDE;
        const int r3 = idx + (it * 4 + 3) * STRIDE;

        const float4 a0 = *reinterpret_cast<const float4*>(logits + (size_t)r0 * 8);
        const float4 b0 = *reinterpret_cast<const float4*>(logits + (size_t)r0 * 8 + 4);
        const float4 a1 = *reinterpret_cast<const float4*>(logits + (size_t)r1 * 8);
        const float4 b1 = *reinterpret_cast<const float4*>(logits + (size_t)r1 * 8 + 4);
        const float4 a2 = *reinterpret_cast<const float4*>(logits + (size_t)r2 * 8);
        const float4 b2 = *reinterpret_cast<const float4*>(logits + (size_t)r2 * 8 + 4);
        const float4 a3 = *reinterpret_cast<const float4*>(logits + (size_t)r3 * 8);
        const float4 b3 = *reinterpret_cast<const float4*>(logits + (size_t)r3 * 8 + 4);
        const int l0 = labels[r0];
        const int l1 = labels[r1];
        const int l2 = labels[r2];
        const int l3 = labels[r3];

        acc += row_loss(a0, b0, l0);
        acc += row_loss(a1, b1, l1);
        acc += row_loss(a2, b2, l2);
        acc += row_loss(a3, b3, l3);
    }

    // wave (64-lane) shuffle reduce
    #pragma unroll
    for (int off = 32; off > 0; off >>= 1)
        acc += __shfl_down(acc, off);

    __shared__ float lds[4];
    const int lane = threadIdx.x & 63;
    const int wid  = threadIdx.x >> 6;
    if (lane == 0) lds[wid] = acc;
    __syncthreads();
    if (threadIdx.x == 0) {
        const float bsum = (lds[0] + lds[1]) + (lds[2] + lds[3]);
        partials[task * NB + blockIdx.x] = bsum;
    }
}

__global__ __launch_bounds__(256) void focal_final_kernel(
    const float* __restrict__ partials, float* __restrict__ out)
{
    double sd = 0.0, sv = 0.0;
    for (int k = threadIdx.x; k < NB; k += 256) {
        sd += (double)partials[k];
        sv += (double)partials[NB + k];
    }
    #pragma unroll
    for (int off = 32; off > 0; off >>= 1) {
        sd += __shfl_down(sd, off);
        sv += __shfl_down(sv, off);
    }
    __shared__ double lds[8];
    const int lane = threadIdx.x & 63;
    const int wid  = threadIdx.x >> 6;
    if (lane == 0) { lds[wid] = sd; lds[4 + wid] = sv; }
    __syncthreads();
    if (threadIdx.x == 0) {
        const double l_dir = ((lds[0] + lds[1]) + (lds[2] + lds[3])) / (double)B_ROWS;
        const double l_vol = ((lds[4] + lds[5]) + (lds[6] + lds[7])) / (double)B_ROWS;
        out[0] = (float)(l_dir + 0.5 * l_vol);  // total = 1.0*dir + 0.5*vol
        out[1] = (float)l_dir;
        out[2] = (float)l_vol;
    }
}

extern "C" void kernel_launch(void* const* d_in, const int* in_sizes, int n_in,
                              void* d_out, int out_size, void* d_ws, size_t ws_size,
                              hipStream_t stream) {
    const float* logits_dir = (const float*)d_in[0];
    const int*   labels_dir = (const int*)d_in[1];
    const float* logits_vol = (const float*)d_in[2];
    const int*   labels_vol = (const int*)d_in[3];
    float* out = (float*)d_out;
    float* partials = (float*)d_ws;  // 2*NB floats = 8 KB, fully overwritten each call

    dim3 grid(NB, 2);
    focal_partial_kernel<<<grid, 256, 0, stream>>>(logits_dir, labels_dir,
                                                   logits_vol, labels_vol, partials);
    focal_final_kernel<<<1, 256, 0, stream>>>(partials, out);
}